// Round 10
// baseline (1009.454 us; speedup 1.0000x reference)
//
#include <hip/hip_runtime.h>

#define HH 192
#define WW 192
#define CC 128
#define BB 8
#define HW (HH * WW)          // 36864
#define OC 8
#define NPIX (BB * HW)        // 294912 per BN channel
#define YCHUNK (OC * BB * HW) // elements per y buffer
#define X0ROW 24576           // elems per (b,row): 2par*6ut*2048
#define X1ROW 28672           // elems per (b,row): 2par*7vt*2048  (57344 B)

typedef __attribute__((ext_vector_type(8))) short bf16x8;
typedef __attribute__((ext_vector_type(4))) float f32x4;

__device__ __forceinline__ unsigned short f2bf(float f) {
    unsigned int u = __float_as_uint(f);
    u += 0x7fffu + ((u >> 16) & 1u);          // RNE
    return (unsigned short)(u >> 16);
}
__device__ __forceinline__ float bf2f(unsigned short u) {
    return __uint_as_float(((unsigned int)u) << 16);
}

// ---------------------------------------------------------------------------
// k_pack: fp32 [b][c][h][w] -> bf16 fragment-ordered tiles (r9 uint4 version).
// x0t[b][i]: 12 tiles (par*6+ut) of 2048, tile=[q(4)][kg(4)][pxl(16)][e(8)].
// x1t[b][r]: 14 tiles (par*7+vt), v = 16*vt-8+pxl, zero outside [0,96).
// ---------------------------------------------------------------------------
__global__ __launch_bounds__(256) void k_pack(
    const float* __restrict__ x0, const float* __restrict__ x1,
    unsigned short* __restrict__ x0t, unsigned short* __restrict__ x1t)
{
    const int h = blockIdx.x, b = blockIdx.y, t = blockIdx.z;
    const float* src = t ? x1 : x0;
    __shared__ unsigned short lds[WW * 130];

    for (int idx = threadIdx.x; idx < CC * WW; idx += 256) {
        const int w = idx % WW, c = idx / WW;      // consecutive w per lane
        lds[w * 130 + c] = f2bf(src[((size_t)(b * CC + c) * HH + h) * WW + w]);
    }
    __syncthreads();

    if (t == 0) {
        uint4* dst = (uint4*)(x0t + (size_t)(b * HH + h) * X0ROW);
        for (int f8 = threadIdx.x; f8 < X0ROW / 8; f8 += 256) {
            const int pxl = f8 & 15;
            const int kg  = (f8 >> 4) & 3;
            const int q   = (f8 >> 6) & 3;
            const int pu  = f8 >> 8;               // par*6 + ut
            const int ut  = pu % 6, par = pu / 6;
            const int px  = 2 * (16 * ut + pxl) + par;
            const unsigned short* s0 = &lds[px * 130 + q * 32 + kg * 8];
            uint4 v;
            v.x = s0[0] | ((unsigned int)s0[1] << 16);
            v.y = s0[2] | ((unsigned int)s0[3] << 16);
            v.z = s0[4] | ((unsigned int)s0[5] << 16);
            v.w = s0[6] | ((unsigned int)s0[7] << 16);
            dst[f8] = v;
        }
    } else {
        uint4* dst = (uint4*)(x1t + (size_t)(b * HH + h) * X1ROW);
        for (int f8 = threadIdx.x; f8 < X1ROW / 8; f8 += 256) {
            const int pxl = f8 & 15;
            const int kg  = (f8 >> 4) & 3;
            const int q   = (f8 >> 6) & 3;
            const int pv  = f8 >> 8;               // par*7 + vt
            const int vt  = pv % 7, par = pv / 7;
            const int v   = 16 * vt - 8 + pxl;
            uint4 val = {0u, 0u, 0u, 0u};
            if (v >= 0 && v < 96) {
                const int px = 2 * v + par;
                const unsigned short* s0 = &lds[px * 130 + q * 32 + kg * 8];
                val.x = s0[0] | ((unsigned int)s0[1] << 16);
                val.y = s0[2] | ((unsigned int)s0[3] << 16);
                val.z = s0[4] | ((unsigned int)s0[5] << 16);
                val.w = s0[6] | ((unsigned int)s0[7] << 16);
            }
            dst[f8] = val;
        }
    }
}

// ---------------------------------------------------------------------------
// K1-MFMA v10: 12 waves (wave = par*6+ut), B-row cooperatively staged into
// LDS double buffer (issue-early global loads, ds_write-late after compute),
// A in 2-deep register buffer. corr bf16 34KB + 2x60KB B = 154KB, 1 blk/CU,
// 12 co-resident waves. split=2 over pi (part0 -> d_out(+bias), part1 -> ws).
// ---------------------------------------------------------------------------
__global__ __launch_bounds__(768, 3) void k_corr_mfma_conv(
    const unsigned short* __restrict__ x0t, const unsigned short* __restrict__ x1t,
    const float* __restrict__ cw, const float* __restrict__ cb,
    float* __restrict__ y0, float* __restrict__ y1)
{
    const int L = blockIdx.x;                     // 512 blocks
    const int w = (L & 7) * 64 + (L >> 3);        // bijective XCD swizzle (512=8*64)
    const int b     = w >> 6;                     // image b pinned to XCD b
    const int rem   = w & 63;
    const int part  = rem >> 5;                   // 0..1
    const int strip = rem & 31;
    const int i0    = strip * 6;
    const int plo   = part ? 6 : 0;
    const int phi   = part ? 11 : 6;

    const int tid  = threadIdx.x;
    const int wave = tid >> 6, lane = tid & 63;   // wave = par*6 + ut
    const int ln15 = lane & 15, kg = lane >> 4;
    const int par  = wave / 6, ut = wave % 6;
    const int u0   = ut * 16;

    __shared__ unsigned short corr[8][194][11];   // 34,144 B; cols 0,193 zero
    __shared__ uint4 Bbuf[2][3840];               // 2 x 61,440 B (56KB row + pad)

    if (tid < 176) {                               // zero pad columns once
        const int ir = tid / 22, rr = tid % 22;
        const int pj = rr % 11, jj = (rr < 11) ? 0 : 193;
        corr[ir][jj][pj] = 0;
    }

    const int quad = tid / 192;                    // 0..3 (quad 3 idle in conv)
    const int jt   = tid % 192;

    float yacc[2][OC];
#pragma unroll
    for (int k = 0; k < 2; ++k)
#pragma unroll
        for (int o = 0; o < OC; ++o) yacc[k][o] = 0.f;

    const unsigned short* x0b = x0t + (size_t)b * HH * X0ROW;
    const unsigned short* x1b = x1t + (size_t)b * HH * X1ROW;

    // stage-load helpers (offsets in bytes within a 57,344 B row)
    const int soff0 = tid * 16;                    // sweep s: soff0 + s*12288

    bf16x8 A[2][4];

    for (int pi = plo; pi < phi; ++pi) {
        // ---- prologue: fetch row(pi, ir=0) + A(0) ----
        {
            const int r0  = min(max(i0 - 1 + 2 * pi - 10, 0), HH - 1);
            const char* rsrc = (const char*)(x1b + (size_t)r0 * X1ROW);
            uint4 R[5];
#pragma unroll
            for (int s = 0; s < 5; ++s) {
                const int off = soff0 + s * 12288;
                if (off < 57344) R[s] = *(const uint4*)(rsrc + off);
            }
            const int icl = min(max(i0 - 1, 0), HH - 1);
            const unsigned short* pa =
                x0b + (size_t)icl * X0ROW + wave * 2048 + lane * 8;
            A[0][0] = *(const bf16x8*)(pa);
            A[0][1] = *(const bf16x8*)(pa + 512);
            A[0][2] = *(const bf16x8*)(pa + 1024);
            A[0][3] = *(const bf16x8*)(pa + 1536);

            __syncthreads();                       // conv(pi-1) readers done
#pragma unroll
            for (int s = 0; s < 5; ++s) {
                const int off = soff0 + s * 12288;
                if (off < 57344) *(uint4*)((char*)&Bbuf[0][0] + off) = R[s];
            }
            __syncthreads();                       // buf0 visible
        }

        // ---- 8 ir steps, staged pipeline ----
#pragma unroll
        for (int ir = 0; ir < 8; ++ir) {
            uint4 R[5];
            if (ir < 7) {
                // issue-early: next row + next A (consumed after barrier)
                const int rn = min(max(i0 + ir + 2 * pi - 10, 0), HH - 1);
                const char* rsrc = (const char*)(x1b + (size_t)rn * X1ROW);
#pragma unroll
                for (int s = 0; s < 5; ++s) {
                    const int off = soff0 + s * 12288;
                    if (off < 57344) R[s] = *(const uint4*)(rsrc + off);
                }
                const int icl = min(max(i0 + ir, 0), HH - 1);
                const unsigned short* pa =
                    x0b + (size_t)icl * X0ROW + wave * 2048 + lane * 8;
                A[(ir + 1) & 1][0] = *(const bf16x8*)(pa);
                A[(ir + 1) & 1][1] = *(const bf16x8*)(pa + 512);
                A[(ir + 1) & 1][2] = *(const bf16x8*)(pa + 1024);
                A[(ir + 1) & 1][3] = *(const bf16x8*)(pa + 1536);
            }

            // ---- compute(ir): MFMA from A regs + LDS B row ----
            {
                const int i = i0 - 1 + ir;
                const int r = i + 2 * pi - 10;
                const bool gv = (i >= 0) && (i < HH) && (r >= 0) && (r < HH);
                const char* bb = (const char*)&Bbuf[ir & 1][0];

#pragma unroll
                for (int vtl = 0; vtl < 2; ++vtl) {
                    const char* pb =
                        bb + (par * 7 + ut + vtl) * 4096 + lane * 16;
                    const bf16x8 b0 = *(const bf16x8*)(pb);
                    const bf16x8 b1 = *(const bf16x8*)(pb + 1024);
                    const bf16x8 b2 = *(const bf16x8*)(pb + 2048);
                    const bf16x8 b3 = *(const bf16x8*)(pb + 3072);

                    f32x4 c = {0.f, 0.f, 0.f, 0.f};
                    c = __builtin_amdgcn_mfma_f32_16x16x32_bf16(A[ir & 1][0], b0, c, 0, 0, 0);
                    c = __builtin_amdgcn_mfma_f32_16x16x32_bf16(A[ir & 1][1], b1, c, 0, 0, 0);
                    c = __builtin_amdgcn_mfma_f32_16x16x32_bf16(A[ir & 1][2], b2, c, 0, 0, 0);
                    c = __builtin_amdgcn_mfma_f32_16x16x32_bf16(A[ir & 1][3], b3, c, 0, 0, 0);

                    const int v = u0 - 8 + 16 * vtl + ln15;  // packed zeros cover OOB v
#pragma unroll
                    for (int rg = 0; rg < 4; ++rg) {
                        const int u  = u0 + kg * 4 + rg;
                        const int pj = v - u + 5;
                        if (pj >= 0 && pj < 11)
                            corr[ir][2 * u + par + 1][pj] = f2bf(gv ? c[rg] : 0.f);
                    }
                }
            }
            __syncthreads();                       // compute(ir) readers done

            if (ir < 7) {                          // write-late into freed buffer
#pragma unroll
                for (int s = 0; s < 5; ++s) {
                    const int off = soff0 + s * 12288;
                    if (off < 57344)
                        *(uint4*)((char*)&Bbuf[(ir + 1) & 1][0] + off) = R[s];
                }
                __syncthreads();                   // next buf visible
            }
        }
        // post-compute(7) barrier above: corr complete & visible

        // ---- conv(3x3, 121->8): quads 0..2, 2 rows each ----
        if (quad < 3) {
            for (int ki = 0; ki < 3; ++ki) {
                for (int kj = 0; kj < 3; ++kj) {
                    float cv[2][11];
#pragma unroll
                    for (int k = 0; k < 2; ++k) {
                        const unsigned short* cp =
                            &corr[quad * 2 + k + ki][jt + kj][0];
#pragma unroll
                        for (int pj = 0; pj < 11; ++pj) cv[k][pj] = bf2f(cp[pj]);
                    }
#pragma unroll
                    for (int o = 0; o < OC; ++o) {
                        float a0 = yacc[0][o], a1 = yacc[1][o];
#pragma unroll
                        for (int pj = 0; pj < 11; ++pj) {
                            const float wv =           // wave-uniform -> s_load
                                cw[o * 1089 + (pi * 11 + pj) * 9 + ki * 3 + kj];
                            a0 = fmaf(wv, cv[0][pj], a0);
                            a1 = fmaf(wv, cv[1][pj], a1);
                        }
                        yacc[0][o] = a0; yacc[1][o] = a1;
                    }
                }
            }
        }
    }

    if (quad < 3) {
        float* yp = part ? y1 : y0;
#pragma unroll
        for (int k = 0; k < 2; ++k) {
            const int irow = i0 + quad * 2 + k;
#pragma unroll
            for (int o = 0; o < OC; ++o) {
                float val = yacc[k][o];
                if (part == 0) val += cb[o];
                yp[((size_t)(b * OC + o) * HH + irow) * WW + jt] = val;
            }
        }
    }
}

// ---------------------------------------------------------------------------
// Fallback K1 (round-1 verified fp32 path) — only if ws too small
// ---------------------------------------------------------------------------
__global__ __launch_bounds__(256) void k_corr_conv(
    const float* __restrict__ x0, const float* __restrict__ x1,
    const float* __restrict__ cw, const float* __restrict__ cb,
    float* __restrict__ y)
{
    const int b  = blockIdx.z;
    const int i0 = blockIdx.y * 14;
    const int j0 = blockIdx.x * 14;
    const int li = threadIdx.x >> 4;
    const int lj = threadIdx.x & 15;
    const int gi = i0 + li - 1;
    const int gj = j0 + lj - 1;
    const bool valid    = (gi >= 0) & (gi < HH) & (gj >= 0) & (gj < WW);
    const bool interior = (li >= 1) & (li <= 14) & (lj >= 1) & (lj <= 14)
                        & (gi < HH) & (gj < WW);

    __shared__ float corr[16][16][13];

    float yacc[OC];
#pragma unroll
    for (int o = 0; o < OC; ++o) yacc[o] = 0.f;

    const size_t bbase = (size_t)b * CC * HW;
    const float* x0p = x0 + bbase + (size_t)gi * WW + gj;

    for (int pi = 0; pi < 11; ++pi) {
        float acc[11];
#pragma unroll
        for (int k = 0; k < 11; ++k) acc[k] = 0.f;

        const int r = gi + 2 * pi - 10;
        if (valid && r >= 0 && r < HH) {
            const float* p0 = x0p;
            if (gj >= 10 && gj <= WW - 11) {
                const float* p1o = x1 + bbase + (size_t)r * WW + (gj - 10);
#pragma unroll 2
                for (int c = 0; c < CC; ++c) {
                    const float a = *p0;
#pragma unroll
                    for (int k = 0; k < 11; ++k)
                        acc[k] = fmaf(a, p1o[2 * k], acc[k]);
                    p0 += HW; p1o += HW;
                }
            } else {
                const float* p1 = x1 + bbase + (size_t)r * WW;
#pragma unroll 2
                for (int c = 0; c < CC; ++c) {
                    const float a = *p0;
#pragma unroll
                    for (int k = 0; k < 11; ++k) {
                        const int col = gj + 2 * k - 10;
                        const float v = (col >= 0 && col < WW) ? p1[col] : 0.f;
                        acc[k] = fmaf(a, v, acc[k]);
                    }
                    p0 += HW; p1 += HW;
                }
            }
        }

        __syncthreads();
#pragma unroll
        for (int k = 0; k < 11; ++k) corr[li][lj][k] = acc[k];
        __syncthreads();

        if (interior) {
#pragma unroll
            for (int ki = 0; ki < 3; ++ki) {
#pragma unroll
                for (int kj = 0; kj < 3; ++kj) {
                    float cv[11];
#pragma unroll
                    for (int k = 0; k < 11; ++k)
                        cv[k] = corr[li + ki - 1][lj + kj - 1][k];
#pragma unroll
                    for (int o = 0; o < OC; ++o) {
#pragma unroll
                        for (int k = 0; k < 11; ++k) {
                            const float wv =
                                cw[(((o * 121) + pi * 11 + k) * 3 + ki) * 3 + kj];
                            yacc[o] = fmaf(wv, cv[k], yacc[o]);
                        }
                    }
                }
            }
        }
    }

    if (interior) {
#pragma unroll
        for (int o = 0; o < OC; ++o)
            y[(size_t)(b * OC + o) * HW + (size_t)gi * WW + gj] = yacc[o] + cb[o];
    }
}

// ---------------------------------------------------------------------------
// BN stats over up to 2 partial-y buffers (deterministic two-stage)
// ---------------------------------------------------------------------------
__global__ __launch_bounds__(256) void k_stats_partial(
    const float* __restrict__ y0, const float* __restrict__ y1, int add2,
    float* __restrict__ st)
{
    const int bid = blockIdx.x;            // b*32 + o*4 + q
    const int b = bid >> 5, rem = bid & 31;
    const int o = rem >> 2, q = rem & 3;
    const size_t off = (size_t)(b * OC + o) * (HW / 4) + q * (HW / 16);
    const float4* p0 = (const float4*)y0 + off;
    const float4* p1 = (const float4*)y1 + off;
    float s = 0.f, qq = 0.f;
    for (int t = threadIdx.x; t < HW / 16; t += 256) {
        float4 z = p0[t];
        if (add2) {
            const float4 v = p1[t];
            z.x += v.x; z.y += v.y; z.z += v.z; z.w += v.w;
        }
        s += z.x + z.y + z.z + z.w;
        qq = fmaf(z.x, z.x, qq); qq = fmaf(z.y, z.y, qq);
        qq = fmaf(z.z, z.z, qq); qq = fmaf(z.w, z.w, qq);
    }
#pragma unroll
    for (int off2 = 32; off2 > 0; off2 >>= 1) {
        s  += __shfl_down(s, off2);
        qq += __shfl_down(qq, off2);
    }
    __shared__ float ss[4], sq[4];
    const int lane = threadIdx.x & 63, wv = threadIdx.x >> 6;
    if (lane == 0) { ss[wv] = s; sq[wv] = qq; }
    __syncthreads();
    if (threadIdx.x == 0) {
        st[bid]       = ss[0] + ss[1] + ss[2] + ss[3];
        st[256 + bid] = sq[0] + sq[1] + sq[2] + sq[3];
    }
}

__global__ void k_stats_final(float* __restrict__ st,
                              const float* __restrict__ gamma,
                              const float* __restrict__ beta)
{
    const int o = threadIdx.x;
    if (o < 8) {
        float S = 0.f, Q = 0.f;
#pragma unroll
        for (int b = 0; b < 8; ++b)
#pragma unroll
            for (int q = 0; q < 4; ++q) {
                S += st[b * 32 + o * 4 + q];
                Q += st[256 + b * 32 + o * 4 + q];
            }
        const float invN = 1.f / (float)NPIX;
        const float mean = S * invN;
        const float var  = Q * invN - mean * mean;
        const float sc   = gamma[o] / sqrtf(var + 1e-5f);
        st[512 + o] = sc;
        st[520 + o] = beta[o] - mean * sc;
    }
}

__global__ __launch_bounds__(256) void k_bn_relu(
    const float* __restrict__ y0, const float* __restrict__ y1, int add2,
    const float* __restrict__ st, float* __restrict__ out)
{
    const int i = blockIdx.x * 256 + threadIdx.x;  // float4 idx, exact grid
    const int o = (i / (HW / 4)) & 7;
    const float sc = st[512 + o], sh = st[520 + o];
    float4 z = ((const float4*)y0)[i];
    if (add2) {
        const float4 v = ((const float4*)y1)[i];
        z.x += v.x; z.y += v.y; z.z += v.z; z.w += v.w;
    }
    float4 r;
    r.x = fmaxf(fmaf(z.x, sc, sh), 0.f);
    r.y = fmaxf(fmaf(z.y, sc, sh), 0.f);
    r.z = fmaxf(fmaf(z.z, sc, sh), 0.f);
    r.w = fmaxf(fmaf(z.w, sc, sh), 0.f);
    ((float4*)out)[i] = r;
}

extern "C" void kernel_launch(void* const* d_in, const int* in_sizes, int n_in,
                              void* d_out, int out_size, void* d_ws, size_t ws_size,
                              hipStream_t stream)
{
    const float* x0    = (const float*)d_in[0];
    const float* x1    = (const float*)d_in[1];
    const float* cw    = (const float*)d_in[2];
    const float* cb    = (const float*)d_in[3];
    const float* gamma = (const float*)d_in[4];
    const float* beta  = (const float*)d_in[5];
    float* out = (float*)d_out;
    float* st  = (float*)d_ws;   // stats scratch reuses ws base (x0t dead by then)

    const size_t x0bytes = (size_t)BB * HH * X0ROW * sizeof(unsigned short); // 72 MiB
    const size_t x1bytes = (size_t)BB * HH * X1ROW * sizeof(unsigned short); // 84 MiB
    const size_t ybytes  = (size_t)YCHUNK * sizeof(float);                   //  9 MiB

    if (ws_size >= x0bytes + x1bytes + ybytes + 65536) {
        unsigned short* x0t = (unsigned short*)d_ws;
        unsigned short* x1t = (unsigned short*)((char*)d_ws + x0bytes);
        float* y1           = (float*)((char*)d_ws + x0bytes + x1bytes);
        // NOTE: v10 stage reads overrun row 191 by <= 4KB into y1 region (allocated).

        k_pack<<<dim3(HH, BB, 2), 256, 0, stream>>>(x0, x1, x0t, x1t);
        k_corr_mfma_conv<<<512, 768, 0, stream>>>(x0t, x1t, cw, cb, out, y1);
        k_stats_partial<<<256, 256, 0, stream>>>(out, y1, 1, st);
        k_stats_final<<<1, 64, 0, stream>>>(st, gamma, beta);
        k_bn_relu<<<(YCHUNK / 4) / 256, 256, 0, stream>>>(out, y1, 1, st, out);
    } else {
        dim3 g1(14, 14, 8);
        k_corr_conv<<<g1, 256, 0, stream>>>(x0, x1, cw, cb, out);
        k_stats_partial<<<256, 256, 0, stream>>>(out, out, 0, st);
        k_stats_final<<<1, 64, 0, stream>>>(st, gamma, beta);
        k_bn_relu<<<(YCHUNK / 4) / 256, 256, 0, stream>>>(out, out, 0, st, out);
    }
}

// Round 11
// 924.112 us; speedup vs baseline: 1.0924x; 1.0924x over previous
//
#include <hip/hip_runtime.h>

#define HH 192
#define WW 192
#define CC 128
#define BB 8
#define HW (HH * WW)          // 36864
#define OC 8
#define NPIX (BB * HW)        // 294912 per BN channel
#define YCHUNK (OC * BB * HW) // elements of y
#define X0ROW 24576           // elems per (b,row): 2par*6ut*2048
#define X1ROW 28672           // elems per (b,row): 2par*7vt*2048

typedef __attribute__((ext_vector_type(8))) short bf16x8;
typedef __attribute__((ext_vector_type(4))) float f32x4;

__device__ __forceinline__ unsigned short f2bf(float f) {
    unsigned int u = __float_as_uint(f);
    u += 0x7fffu + ((u >> 16) & 1u);          // RNE
    return (unsigned short)(u >> 16);
}
__device__ __forceinline__ float bf2f(unsigned short u) {
    return __uint_as_float(((unsigned int)u) << 16);
}

// ---------------------------------------------------------------------------
// k_pack: fp32 [b][c][h][w] -> bf16 fragment-ordered tiles (r9/r10 version).
// x0t[b][i]: 12 tiles (par*6+ut) of 2048, tile=[q(4)][kg(4)][pxl(16)][e(8)].
// x1t[b][r]: 14 tiles (par*7+vt), v = 16*vt-8+pxl, zero outside [0,96).
// ---------------------------------------------------------------------------
__global__ __launch_bounds__(256) void k_pack(
    const float* __restrict__ x0, const float* __restrict__ x1,
    unsigned short* __restrict__ x0t, unsigned short* __restrict__ x1t)
{
    const int h = blockIdx.x, b = blockIdx.y, t = blockIdx.z;
    const float* src = t ? x1 : x0;
    __shared__ unsigned short lds[WW * 130];

    for (int idx = threadIdx.x; idx < CC * WW; idx += 256) {
        const int w = idx % WW, c = idx / WW;      // consecutive w per lane
        lds[w * 130 + c] = f2bf(src[((size_t)(b * CC + c) * HH + h) * WW + w]);
    }
    __syncthreads();

    if (t == 0) {
        uint4* dst = (uint4*)(x0t + (size_t)(b * HH + h) * X0ROW);
        for (int f8 = threadIdx.x; f8 < X0ROW / 8; f8 += 256) {
            const int pxl = f8 & 15;
            const int kg  = (f8 >> 4) & 3;
            const int q   = (f8 >> 6) & 3;
            const int pu  = f8 >> 8;               // par*6 + ut
            const int ut  = pu % 6, par = pu / 6;
            const int px  = 2 * (16 * ut + pxl) + par;
            const unsigned short* s0 = &lds[px * 130 + q * 32 + kg * 8];
            uint4 v;
            v.x = s0[0] | ((unsigned int)s0[1] << 16);
            v.y = s0[2] | ((unsigned int)s0[3] << 16);
            v.z = s0[4] | ((unsigned int)s0[5] << 16);
            v.w = s0[6] | ((unsigned int)s0[7] << 16);
            dst[f8] = v;
        }
    } else {
        uint4* dst = (uint4*)(x1t + (size_t)(b * HH + h) * X1ROW);
        for (int f8 = threadIdx.x; f8 < X1ROW / 8; f8 += 256) {
            const int pxl = f8 & 15;
            const int kg  = (f8 >> 4) & 3;
            const int q   = (f8 >> 6) & 3;
            const int pv  = f8 >> 8;               // par*7 + vt
            const int vt  = pv % 7, par = pv / 7;
            const int v   = 16 * vt - 8 + pxl;
            uint4 val = {0u, 0u, 0u, 0u};
            if (v >= 0 && v < 96) {
                const int px = 2 * v + par;
                const unsigned short* s0 = &lds[px * 130 + q * 32 + kg * 8];
                val.x = s0[0] | ((unsigned int)s0[1] << 16);
                val.y = s0[2] | ((unsigned int)s0[3] << 16);
                val.z = s0[4] | ((unsigned int)s0[5] << 16);
                val.w = s0[6] | ((unsigned int)s0[7] << 16);
            }
            dst[f8] = val;
        }
    }
}

// ---------------------------------------------------------------------------
// k_corr: barrier-free band-GEMM. Block = (b, 8-row strip, pi), 6 waves
// (wave = ut). Per (wave, ir): 24 dense loads -> 16 MFMA -> band extract into
// per-wave LDS scratch [32][12] -> one coalesced 768 B global write.
// corr_g layout: [pislot][b][i][px(192)][12] bf16 (hw 11 is pad, unused).
// ---------------------------------------------------------------------------
__global__ __launch_bounds__(384, 6) void k_corr(
    const unsigned short* __restrict__ x0t, const unsigned short* __restrict__ x1t,
    unsigned short* __restrict__ corr_g, int pi_base, int npi)
{
    const int L = blockIdx.x;
    const int N = gridDim.x;                       // 8 * 24 * npi, N % 8 == 0
    const int w = (L & 7) * (N >> 3) + (L >> 3);   // bijective XCD swizzle
    const int M = 24 * npi;
    const int b   = w / M;                         // image b pinned to XCD b
    const int m   = w % M;                         // strip-major, pi-inner:
    const int s   = m / npi;                       //   B-row window shared in L2
    const int pis = m % npi;
    const int pi  = pi_base + pis;
    const int i0  = s * 8;

    const int tid  = threadIdx.x;
    const int wave = tid >> 6, lane = tid & 63;    // wave = ut
    const int ln15 = lane & 15, kg = lane >> 4;
    const int ut   = wave;

    __shared__ unsigned short scr[6][32][12];      // 4.6 KB total, per-wave

    const unsigned short* x0b = x0t + (size_t)b * HH * X0ROW;
    const unsigned short* x1b = x1t + (size_t)b * HH * X1ROW;

    for (int ir = 0; ir < 8; ++ir) {
        const int i = i0 + ir;                     // always in [0,192)
        const int r = i + 2 * pi - 10;
        unsigned short* gout = corr_g +
            ((((size_t)pis * BB + b) * HH + i) * WW + 32 * ut) * 12;

        if (r >= 0 && r < HH) {
#pragma unroll
            for (int par = 0; par < 2; ++par) {
                const unsigned short* pa =
                    x0b + (size_t)i * X0ROW + (par * 6 + ut) * 2048 + lane * 8;
                const bf16x8 a0 = *(const bf16x8*)(pa);
                const bf16x8 a1 = *(const bf16x8*)(pa + 512);
                const bf16x8 a2 = *(const bf16x8*)(pa + 1024);
                const bf16x8 a3 = *(const bf16x8*)(pa + 1536);

#pragma unroll
                for (int vtl = 0; vtl < 2; ++vtl) {
                    const unsigned short* pb =
                        x1b + (size_t)r * X1ROW + (par * 7 + ut + vtl) * 2048 + lane * 8;
                    const bf16x8 b0 = *(const bf16x8*)(pb);
                    const bf16x8 b1 = *(const bf16x8*)(pb + 512);
                    const bf16x8 b2 = *(const bf16x8*)(pb + 1024);
                    const bf16x8 b3 = *(const bf16x8*)(pb + 1536);

                    f32x4 c = {0.f, 0.f, 0.f, 0.f};
                    c = __builtin_amdgcn_mfma_f32_16x16x32_bf16(a0, b0, c, 0, 0, 0);
                    c = __builtin_amdgcn_mfma_f32_16x16x32_bf16(a1, b1, c, 0, 0, 0);
                    c = __builtin_amdgcn_mfma_f32_16x16x32_bf16(a2, b2, c, 0, 0, 0);
                    c = __builtin_amdgcn_mfma_f32_16x16x32_bf16(a3, b3, c, 0, 0, 0);

                    // v OOB already zero in x1t; band extract covers pj 0..10
#pragma unroll
                    for (int rg = 0; rg < 4; ++rg) {
                        const int pj = 16 * vtl + ln15 - 4 * kg - rg - 3;
                        if (pj >= 0 && pj < 11)
                            scr[wave][2 * (kg * 4 + rg) + par][pj] = f2bf(c[rg]);
                    }
                }
            }
            // coalesced write: 48 lanes x 16 B = [32 px][12 hw] slice
            if (lane < 48)
                *((uint4*)gout + lane) = *((const uint4*)&scr[wave][0][0] + lane);
        } else {
            if (lane < 48) {
                const uint4 z = {0u, 0u, 0u, 0u};
                *((uint4*)gout + lane) = z;
            }
        }
    }
}

// ---------------------------------------------------------------------------
// k_conv: 3x3x(121->8) conv from corr_g. Block = (b, 2-row strip), 384 thr
// (1 px each). Stages [4][194][12] slab per pi, accumulates y in-place
// (init: +bias; else RMW). Fuses BN partial sums on the final chunk.
// ---------------------------------------------------------------------------
__global__ __launch_bounds__(384) void k_conv(
    const unsigned short* __restrict__ corr_g,
    const float* __restrict__ cw, const float* __restrict__ cb,
    float* __restrict__ y, float* __restrict__ st,
    int pi_base, int npi, int init, int do_stats)
{
    const int L = blockIdx.x;                      // 768 blocks
    const int w = (L & 7) * 96 + (L >> 3);         // XCD swizzle
    const int b  = w / 96;
    const int s2 = w % 96;
    const int i0 = s2 * 2;

    const int tid = threadIdx.x;
    const int row = tid / 192, col = tid % 192;

    __shared__ unsigned short slab[4][194][12];    // 18,624 B
    __shared__ float red[6][16];

    float yacc[OC];
#pragma unroll
    for (int o = 0; o < OC; ++o) yacc[o] = 0.f;

    unsigned int* sw = (unsigned int*)&slab[0][0][0];

    for (int pis = 0; pis < npi; ++pis) {
        const int pi = pi_base + pis;
        __syncthreads();                           // prev slab reads done
        const unsigned int* gsrc = (const unsigned int*)corr_g
                                 + ((size_t)pis * BB + b) * ((size_t)HH * WW * 6);
#pragma unroll
        for (int k = 0; k < 13; ++k) {
            const int w2 = tid + k * 384;
            if (w2 < 4656) {                       // 4*194*6 words
                const int r   = w2 / 1164;
                const int rem = w2 % 1164;
                const int px  = rem / 6;
                const int hwp = rem % 6;
                const int gi  = i0 - 1 + r;
                unsigned int val = 0;
                if (gi >= 0 && gi < HH && px >= 1 && px <= WW)
                    val = gsrc[((size_t)gi * WW + (px - 1)) * 6 + hwp];
                sw[w2] = val;
            }
        }
        __syncthreads();

        for (int ki = 0; ki < 3; ++ki) {
            const unsigned short* cp0 = &slab[row + ki][col][0];
            for (int kj = 0; kj < 3; ++kj) {
                const unsigned short* cp = cp0 + kj * 12;
                float cv[11];
#pragma unroll
                for (int pj = 0; pj < 11; ++pj) cv[pj] = bf2f(cp[pj]);
#pragma unroll
                for (int o = 0; o < OC; ++o) {
                    float acc = yacc[o];
#pragma unroll
                    for (int pj = 0; pj < 11; ++pj) {
                        const float wv =           // wave-uniform -> s_load
                            cw[o * 1089 + (pi * 11 + pj) * 9 + ki * 3 + kj];
                        acc = fmaf(wv, cv[pj], acc);
                    }
                    yacc[o] = acc;
                }
            }
        }
    }

    // write / accumulate y; collect final values for fused BN stats
    float fin[OC];
    float* yp = y + ((size_t)b * OC * HH + (i0 + row)) * WW + col;
#pragma unroll
    for (int o = 0; o < OC; ++o) {
        const float v = yacc[o] + (init ? cb[o] : yp[(size_t)o * HW]);
        yp[(size_t)o * HW] = v;
        fin[o] = v;
    }

    if (do_stats) {
        const int lane = tid & 63, wv = tid >> 6;
#pragma unroll
        for (int o = 0; o < OC; ++o) {
            float s = fin[o];
            float q = fin[o] * fin[o];
#pragma unroll
            for (int off = 32; off > 0; off >>= 1) {
                s += __shfl_down(s, off);
                q += __shfl_down(q, off);
            }
            if (lane == 0) { red[wv][o] = s; red[wv][8 + o] = q; }
        }
        __syncthreads();
        if (tid < 16) {
            const float t = red[0][tid] + red[1][tid] + red[2][tid]
                          + red[3][tid] + red[4][tid] + red[5][tid];
            const int blk = b * 96 + s2;           // 0..767
            st[((tid & 8) ? 6144 : 0) + (tid & 7) * 768 + blk] = t;
        }
    }
}

// ---------------------------------------------------------------------------
// BN finalize (reduce 768 block partials) + apply
// ---------------------------------------------------------------------------
__global__ void k_stats_final2(const float* __restrict__ st,
                               const float* __restrict__ gamma,
                               const float* __restrict__ beta,
                               float* __restrict__ stf)
{
    __shared__ float aS[8][33], aQ[8][33];
    const int o = threadIdx.x & 7, idx = threadIdx.x >> 3;   // 256 threads
    float S = 0.f, Q = 0.f;
    for (int k = 0; k < 24; ++k) {
        S += st[o * 768 + idx + 32 * k];
        Q += st[6144 + o * 768 + idx + 32 * k];
    }
    aS[o][idx] = S; aQ[o][idx] = Q;
    __syncthreads();
    if (threadIdx.x < 8) {
        float SS = 0.f, QQ = 0.f;
        for (int k = 0; k < 32; ++k) { SS += aS[threadIdx.x][k]; QQ += aQ[threadIdx.x][k]; }
        const float invN = 1.f / (float)NPIX;
        const float mean = SS * invN;
        const float var  = QQ * invN - mean * mean;
        const float sc   = gamma[threadIdx.x] / sqrtf(var + 1e-5f);
        stf[threadIdx.x]     = sc;
        stf[8 + threadIdx.x] = beta[threadIdx.x] - mean * sc;
    }
}

__global__ __launch_bounds__(256) void k_bn_apply(
    float* __restrict__ y, const float* __restrict__ stf)
{
    const int i = blockIdx.x * 256 + threadIdx.x;  // float4 idx, exact grid
    const int o = (i / (HW / 4)) & 7;
    const float sc = stf[o], sh = stf[8 + o];
    float4 v = ((float4*)y)[i];
    v.x = fmaxf(fmaf(v.x, sc, sh), 0.f);
    v.y = fmaxf(fmaf(v.y, sc, sh), 0.f);
    v.z = fmaxf(fmaf(v.z, sc, sh), 0.f);
    v.w = fmaxf(fmaf(v.w, sc, sh), 0.f);
    ((float4*)y)[i] = v;
}

// ---------------------------------------------------------------------------
// Fallback (tiny ws): round-1 verified fp32 path + its stats
// ---------------------------------------------------------------------------
__global__ __launch_bounds__(256) void k_corr_conv(
    const float* __restrict__ x0, const float* __restrict__ x1,
    const float* __restrict__ cw, const float* __restrict__ cb,
    float* __restrict__ y)
{
    const int b  = blockIdx.z;
    const int i0 = blockIdx.y * 14;
    const int j0 = blockIdx.x * 14;
    const int li = threadIdx.x >> 4;
    const int lj = threadIdx.x & 15;
    const int gi = i0 + li - 1;
    const int gj = j0 + lj - 1;
    const bool valid    = (gi >= 0) & (gi < HH) & (gj >= 0) & (gj < WW);
    const bool interior = (li >= 1) & (li <= 14) & (lj >= 1) & (lj <= 14)
                        & (gi < HH) & (gj < WW);

    __shared__ float corr[16][16][13];

    float yacc[OC];
#pragma unroll
    for (int o = 0; o < OC; ++o) yacc[o] = 0.f;

    const size_t bbase = (size_t)b * CC * HW;
    const float* x0p = x0 + bbase + (size_t)gi * WW + gj;

    for (int pi = 0; pi < 11; ++pi) {
        float acc[11];
#pragma unroll
        for (int k = 0; k < 11; ++k) acc[k] = 0.f;

        const int r = gi + 2 * pi - 10;
        if (valid && r >= 0 && r < HH) {
            const float* p0 = x0p;
            if (gj >= 10 && gj <= WW - 11) {
                const float* p1o = x1 + bbase + (size_t)r * WW + (gj - 10);
#pragma unroll 2
                for (int c = 0; c < CC; ++c) {
                    const float a = *p0;
#pragma unroll
                    for (int k = 0; k < 11; ++k)
                        acc[k] = fmaf(a, p1o[2 * k], acc[k]);
                    p0 += HW; p1o += HW;
                }
            } else {
                const float* p1 = x1 + bbase + (size_t)r * WW;
#pragma unroll 2
                for (int c = 0; c < CC; ++c) {
                    const float a = *p0;
#pragma unroll
                    for (int k = 0; k < 11; ++k) {
                        const int colx = gj + 2 * k - 10;
                        const float v = (colx >= 0 && colx < WW) ? p1[colx] : 0.f;
                        acc[k] = fmaf(a, v, acc[k]);
                    }
                    p0 += HW; p1 += HW;
                }
            }
        }

        __syncthreads();
#pragma unroll
        for (int k = 0; k < 11; ++k) corr[li][lj][k] = acc[k];
        __syncthreads();

        if (interior) {
#pragma unroll
            for (int ki = 0; ki < 3; ++ki) {
#pragma unroll
                for (int kj = 0; kj < 3; ++kj) {
                    float cv[11];
#pragma unroll
                    for (int k = 0; k < 11; ++k)
                        cv[k] = corr[li + ki - 1][lj + kj - 1][k];
#pragma unroll
                    for (int o = 0; o < OC; ++o) {
#pragma unroll
                        for (int k = 0; k < 11; ++k) {
                            const float wv =
                                cw[(((o * 121) + pi * 11 + k) * 3 + ki) * 3 + kj];
                            yacc[o] = fmaf(wv, cv[k], yacc[o]);
                        }
                    }
                }
            }
        }
    }

    if (interior) {
#pragma unroll
        for (int o = 0; o < OC; ++o)
            y[(size_t)(b * OC + o) * HW + (size_t)gi * WW + gj] = yacc[o] + cb[o];
    }
}

__global__ __launch_bounds__(256) void k_stats_partial_fb(
    const float* __restrict__ y, float* __restrict__ ws)
{
    const int o = blockIdx.x & 7;
    const int b = blockIdx.x >> 3;
    const float4* p = (const float4*)(y + (size_t)(b * OC + o) * HW);
    float s = 0.f, q = 0.f;
    for (int t = threadIdx.x; t < HW / 4; t += 256) {
        const float4 v = p[t];
        s += v.x + v.y + v.z + v.w;
        q = fmaf(v.x, v.x, q); q = fmaf(v.y, v.y, q);
        q = fmaf(v.z, v.z, q); q = fmaf(v.w, v.w, q);
    }
#pragma unroll
    for (int off = 32; off > 0; off >>= 1) {
        s += __shfl_down(s, off);
        q += __shfl_down(q, off);
    }
    __shared__ float ss[4], sq[4];
    const int lane = threadIdx.x & 63, wv = threadIdx.x >> 6;
    if (lane == 0) { ss[wv] = s; sq[wv] = q; }
    __syncthreads();
    if (threadIdx.x == 0) {
        ws[blockIdx.x]      = ss[0] + ss[1] + ss[2] + ss[3];
        ws[64 + blockIdx.x] = sq[0] + sq[1] + sq[2] + sq[3];
    }
}

__global__ void k_stats_final_fb(float* __restrict__ ws,
                                 const float* __restrict__ gamma,
                                 const float* __restrict__ beta)
{
    const int o = threadIdx.x;
    if (o < 8) {
        float S = 0.f, Q = 0.f;
#pragma unroll
        for (int b = 0; b < 8; ++b) {
            S += ws[b * 8 + o];
            Q += ws[64 + b * 8 + o];
        }
        const float invN = 1.f / (float)NPIX;
        const float mean = S * invN;
        const float var  = Q * invN - mean * mean;
        const float sc   = gamma[o] / sqrtf(var + 1e-5f);
        ws[128 + o] = sc;
        ws[136 + o] = beta[o] - mean * sc;
    }
}

extern "C" void kernel_launch(void* const* d_in, const int* in_sizes, int n_in,
                              void* d_out, int out_size, void* d_ws, size_t ws_size,
                              hipStream_t stream)
{
    const float* x0    = (const float*)d_in[0];
    const float* x1    = (const float*)d_in[1];
    const float* cw    = (const float*)d_in[2];
    const float* cb    = (const float*)d_in[3];
    const float* gamma = (const float*)d_in[4];
    const float* beta  = (const float*)d_in[5];
    float* out = (float*)d_out;

    const size_t x0b_ = (size_t)BB * HH * X0ROW * 2;          // 75,497,472
    const size_t x1b_ = (size_t)BB * HH * X1ROW * 2;          // 88,080,384
    const size_t slot = (size_t)BB * HH * WW * 12 * 2;        //  7,077,888
    const size_t stb  = 65536;
    const size_t need_full  = x0b_ + x1b_ + 11 * slot + stb;  // ~241.6 MB
    const size_t need_chunk = x0b_ + x1b_ + 2 * slot + stb;   // ~177.8 MB (proven fits)

    if (ws_size >= need_chunk) {
        const int nslots = (ws_size >= need_full) ? 11 : 2;
        unsigned short* x0t    = (unsigned short*)d_ws;
        unsigned short* x1t    = (unsigned short*)((char*)d_ws + x0b_);
        unsigned short* corr_g = (unsigned short*)((char*)d_ws + x0b_ + x1b_);
        float* st              = (float*)((char*)d_ws + x0b_ + x1b_ + nslots * slot);
        float* stf             = st + 12288;

        k_pack<<<dim3(HH, BB, 2), 256, 0, stream>>>(x0, x1, x0t, x1t);

        int base = 0;
        while (base < 11) {
            int npi = 11 - base;
            if (npi > nslots) npi = nslots;
            k_corr<<<24 * npi * 8, 384, 0, stream>>>(x0t, x1t, corr_g, base, npi);
            k_conv<<<768, 384, 0, stream>>>(corr_g, cw, cb, out, st,
                                            base, npi, base == 0,
                                            (base + npi == 11) ? 1 : 0);
            base += npi;
        }
        k_stats_final2<<<1, 256, 0, stream>>>(st, gamma, beta, stf);
        k_bn_apply<<<(YCHUNK / 4) / 256, 256, 0, stream>>>(out, stf);
    } else {
        float* ws = (float*)d_ws;  // 576 B
        dim3 g1(14, 14, 8);
        k_corr_conv<<<g1, 256, 0, stream>>>(x0, x1, cw, cb, out);
        k_stats_partial_fb<<<64, 256, 0, stream>>>(out, ws);
        k_stats_final_fb<<<1, 64, 0, stream>>>(ws, gamma, beta);
        k_bn_apply<<<(YCHUNK / 4) / 256, 256, 0, stream>>>(out, ws + 128);
    }
}